// Round 11
// baseline (152.000 us; speedup 1.0000x reference)
//
#include <hip/hip_runtime.h>
#include <math.h>

// (B,P,V,F,H) = (32,512,32,16,64). Round 15: NO-WORKSPACE single kernel.
// Decomposition of bench dur across v5-v14: bench ~= fused + 69us CONSTANT
// (v10 46->114.8, v12 70->144, v13 73->149, slope 1.0). Traces show
// fillBufferAligned dispatches of 262144 KB = 256 MiB (~44us each) every
// iteration: the harness RE-POISONS d_ws (rigor.md semantics). We use
// 100 KB of it; the poison costs ~44us/iter + prep dispatch + gaps = the
// constant. Experiment: touch d_ws NOWHERE.
//  - v10/v14 structure verbatim (best fused, 46us, HW-validated layout);
//  - W frags read DIRECTLY from raw W1/W2/W3: per-lane base pointer, each
//    frag = 2 global_load_dwordx4 at compile-time imm offsets + 4 pkrtz
//    (identical rtz conversion to the old prep => identical numerics);
//    W is 4-32 KB per matrix -> L1/L2-resident after first touch;
//  - masks packed in-kernel: readfirstlane-forced scalar loads + SALU
//    compares (scalar pipe, overlaps VALU);
//  - no prep kernel, no d_ws reference at all.
// Predict: fused 46->48-53us; bench ~72-85 if poison is usage-conditional,
// ~116-120 if unconditional (then the 70us is fixed harness cost and the
// fused kernel itself is the only remaining lever).
// MFMA 32x32x16_f16: A[m=l&31][k=8*(l>>5)+j], B[k][n=l&31],
//                    D[row=(r&3)+8*(r>>2)+4*(l>>5)][col=l&31].
namespace {

typedef _Float16 f16x8 __attribute__((ext_vector_type(8)));
typedef _Float16 f16x2 __attribute__((ext_vector_type(2)));
typedef float    f32x16 __attribute__((ext_vector_type(16)));
typedef unsigned int uint;

__device__ __forceinline__ uint pkrtz(float a, float b) {
    return __builtin_bit_cast(uint, __builtin_amdgcn_cvt_pkrtz(a, b));
}
__device__ __forceinline__ uint pk_add(uint a, uint b) {
    uint r; asm("v_pk_add_f16 %0, %1, %2" : "=v"(r) : "v"(a), "v"(b)); return r;
}
__device__ __forceinline__ uint pk_mul(uint a, uint b) {
    uint r; asm("v_pk_mul_f16 %0, %1, %2" : "=v"(r) : "v"(a), "v"(b)); return r;
}
__device__ __forceinline__ uint pk_max(uint a, uint b) {
    uint r; asm("v_pk_max_f16 %0, %1, %2" : "=v"(r) : "v"(a), "v"(b)); return r;
}

__global__ __launch_bounds__(256, 3) void fused_mlp_v15(
    const float* __restrict__ X, const int* __restrict__ M,
    const float* __restrict__ W1, const float* __restrict__ B1,
    const float* __restrict__ W2, const float* __restrict__ B2,
    const float* __restrict__ W3, const float* __restrict__ B3,
    float* __restrict__ OUT)
{
    __shared__ __align__(16) unsigned char sXb[4][2][4096];  // 32768 B
    __shared__ __align__(16) _Float16 sP[4][2][64];          //  1024 B

    const int t = threadIdx.x, w = t >> 6, l = t & 63;
    const int hb = l >> 5, mtl = (l >> 4) & 1;
    const size_t bp0 = (size_t)blockIdx.x * 8 + w * 2;

    unsigned char* sb[2] = { &sXb[w][0][0], &sXb[w][1][0] };
    _Float16*     pl[2] = { &sP[w][0][0],  &sP[w][1][0]  };

    // write base (byte): rows m..m+3 at col n -> one b64. Lane-const XOR
    // swizzle component folded in; nt2 component via wb1 = (wb0+512)^64.
    uint wb0 = (uint)((l & 7) * 32 + mtl * 256 + ((l >> 3) & 1) * 1024 + hb * 8);
    wb0 ^= (uint)(mtl << 5);
    const uint wb1 = (wb0 + 512u) ^ 64u;
    // read base: + 256*ki + 32*(j^ki) gives dword of (m&~1,m|1) at feature n.
    const uint rb = (uint)(mtl * 2048 + hb * 1024 + ((l & 15) >> 1) * 4);
    const uint sel = (l & 1) ? 0x07060302u : 0x05040100u;  // pick own f16 half
    const uint SL2 = pkrtz(0.01f, 0.01f);

    // ---- masks packed in-kernel (scalar path: uniform loads + SALU) ----
    bool anyv[2]; uint adm[2][4][2];
    #pragma unroll
    for (int u = 0; u < 2; ++u) {
        const uint* Mu = (const uint*)M
            + (size_t)__builtin_amdgcn_readfirstlane((uint)(bp0 + u)) * 32;
        uint mk = 0;
        #pragma unroll
        for (int i = 0; i < 32; ++i) mk |= (Mu[i] ? 1u : 0u) << i;
        anyv[u] = (mk != 0u);
        #pragma unroll
        for (int g = 0; g < 4; ++g) {   // rows 8g+4hb .. +3
            uint nib = (mk >> (8 * g + 4 * hb)) & 15u;
            adm[u][g][0] = (nib & 1u ? 0u : 0xFC00u) | (nib & 2u ? 0u : 0xFC000000u);
            adm[u][g][1] = (nib & 4u ? 0u : 0xFC00u) | (nib & 8u ? 0u : 0xFC000000u);
        }
    }

    // ---- W-frag loader: 8 consecutive f32 at p -> f16x8 (rtz, = old prep) ----
    auto cvt8 = [&](const float* __restrict__ p) -> f16x8 {
        float4 f0 = *(const float4*)p;
        float4 f1 = *(const float4*)(p + 4);
        uint4 q;
        q.x = pkrtz(f0.x, f0.y); q.y = pkrtz(f0.z, f0.w);
        q.z = pkrtz(f1.x, f1.y); q.w = pkrtz(f1.z, f1.w);
        return __builtin_bit_cast(f16x8, q);
    };
    // lane base pointers: frag(ki,nt2) of Wm is at base + nt2*32*K + ki*16
    const float* w1b = W1 + (l & 31) * 16  + 8 * hb;   // K=16
    const float* w2b = W2 + (l & 31) * 128 + 8 * hb;   // K=128
    const float* w3b = W3 + (l & 31) * 128 + 8 * hb;

    // ---- X -> layer-1 A-frags (f16, rtz) ----
    f16x8 a1f[2];
    #pragma unroll
    for (int u = 0; u < 2; ++u) {
        const float4* xp = (const float4*)(X + ((bp0 + u) * 32 + (l & 31)) * 16 + 8 * hb);
        float4 x0 = xp[0], x1 = xp[1];
        uint4 q;
        q.x = pkrtz(x0.x, x0.y); q.y = pkrtz(x0.z, x0.w);
        q.z = pkrtz(x1.x, x1.y); q.w = pkrtz(x1.z, x1.w);
        a1f[u] = __builtin_bit_cast(f16x8, q);
    }

    // persistent zero C-input (16 regs, init once)
    f32x16 zc;
    #pragma unroll
    for (int i = 0; i < 16; ++i) zc[i] = 0.f;

    f32x16 acc[2][2];   // [u][nt2]

    // ---- layer 1 (K=16, one 32x32x16 step, no padding) ----
    {
        f16x8 wf0 = cvt8(w1b);          // nt2=0
        f16x8 wf1 = cvt8(w1b + 512);    // nt2=1 (32 rows x 16)
        #pragma unroll
        for (int u = 0; u < 2; ++u) {
            acc[u][0] = __builtin_amdgcn_mfma_f32_32x32x16_f16(a1f[u], wf0, zc, 0, 0, 0);
            acc[u][1] = __builtin_amdgcn_mfma_f32_32x32x16_f16(a1f[u], wf1, zc, 0, 0, 0);
        }
    }

    // ---- epilogue: +bias, lrelu, (store h to swizzled LDS), masked pool ----
    auto epi = [&](int u, const float* __restrict__ Bp, bool dostore) {
        unsigned char* sbu = sb[u];
        _Float16* plu = pl[u];
        #pragma unroll
        for (int nt2 = 0; nt2 < 2; ++nt2) {
            float bsc = Bp[32 * nt2 + (l & 31)];
            uint bpk = pkrtz(bsc, bsc);
            uint base = nt2 ? wb1 : wb0;
            uint pp = 0xFC00FC00u;   // (-inf, -inf)
            #pragma unroll
            for (int g = 0; g < 4; ++g) {   // rows m = 8g+4hb .. +3
                uint d01 = pkrtz(acc[u][nt2][4 * g + 0], acc[u][nt2][4 * g + 1]);
                uint d23 = pkrtz(acc[u][nt2][4 * g + 2], acc[u][nt2][4 * g + 3]);
                d01 = pk_add(d01, bpk);  d23 = pk_add(d23, bpk);
                d01 = pk_max(d01, pk_mul(d01, SL2));      // packed lrelu
                d23 = pk_max(d23, pk_mul(d23, SL2));
                if (dostore) {
                    uint2 st; st.x = d01; st.y = d23;
                    *(uint2*)(sbu + base + (g >> 1) * 2048 + (g & 1) * 16) = st;
                }
                pp = pk_max(pp, pk_add(d01, adm[u][g][0]));
                pp = pk_max(pp, pk_add(d23, adm[u][g][1]));
            }
            f16x2 ph = __builtin_bit_cast(f16x2, pp);
            float pv = fmaxf((float)ph[0], (float)ph[1]);
            pv = fmaxf(pv, __shfl_xor(pv, 32));   // merge other hb half
            pv = anyv[u] ? pv : 0.f;
            if (dostore) {
                if (l < 32) plu[32 * nt2 + (l & 31)] = (_Float16)pv;
            } else {
                if (l < 32) OUT[(bp0 + u) * 64 + 32 * nt2 + (l & 31)] = pv;
            }
        }
    };

    // ---- K=128 layer: ki 0..3 from swizzled h, ki 4..7 from pool bcast ----
    auto layerK = [&](const float* __restrict__ wmb) {
        #pragma unroll
        for (int ki = 0; ki < 8; ++ki) {
            f16x8 wf0 = cvt8(wmb + ki * 16);           // nt2=0
            f16x8 wf1 = cvt8(wmb + 4096 + ki * 16);    // nt2=1 (32 rows x 128)
            #pragma unroll
            for (int u = 0; u < 2; ++u) {
                f16x8 a;
                if (ki < 4) {
                    const unsigned char* p = sb[u] + rb + 256 * ki;
                    uint F0 = *(const uint*)(p + 32 * (0 ^ ki));
                    uint F1 = *(const uint*)(p + 32 * (1 ^ ki));
                    uint F2 = *(const uint*)(p + 32 * (2 ^ ki));
                    uint F3 = *(const uint*)(p + 32 * (3 ^ ki));
                    uint F4 = *(const uint*)(p + 32 * (4 ^ ki));
                    uint F5 = *(const uint*)(p + 32 * (5 ^ ki));
                    uint F6 = *(const uint*)(p + 32 * (6 ^ ki));
                    uint F7 = *(const uint*)(p + 32 * (7 ^ ki));
                    uint4 q;
                    q.x = __builtin_amdgcn_perm(F1, F0, sel);
                    q.y = __builtin_amdgcn_perm(F3, F2, sel);
                    q.z = __builtin_amdgcn_perm(F5, F4, sel);
                    q.w = __builtin_amdgcn_perm(F7, F6, sel);
                    a = __builtin_bit_cast(f16x8, q);
                } else {
                    a = *(const f16x8*)(pl[u] + 16 * (ki - 4) + 8 * hb);  // bcast
                }
                acc[u][0] = __builtin_amdgcn_mfma_f32_32x32x16_f16(
                    a, wf0, ki == 0 ? zc : acc[u][0], 0, 0, 0);
                acc[u][1] = __builtin_amdgcn_mfma_f32_32x32x16_f16(
                    a, wf1, ki == 0 ? zc : acc[u][1], 0, 0, 0);
            }
        }
    };

    epi(0, B1, true);  epi(1, B1, true);
    layerK(w2b);
    epi(0, B2, true);  epi(1, B2, true);
    layerK(w3b);
    epi(0, B3, false); epi(1, B3, false);   // layer-3 pool == final output
}
} // namespace

extern "C" void kernel_launch(void* const* d_in, const int* in_sizes, int n_in,
                              void* d_out, int out_size, void* d_ws, size_t ws_size,
                              hipStream_t stream) {
    (void)in_sizes; (void)n_in; (void)d_ws; (void)ws_size; (void)out_size;
    const float* X  = (const float*)d_in[0];
    const int*   M  = (const int*)d_in[1];
    const float* W1 = (const float*)d_in[2];
    const float* B1 = (const float*)d_in[3];
    const float* W2 = (const float*)d_in[4];
    const float* B2 = (const float*)d_in[5];
    const float* W3 = (const float*)d_in[6];
    const float* B3 = (const float*)d_in[7];
    float* OUT = (float*)d_out;

    // Single dispatch; d_ws is NEVER touched (tests whether the harness's
    // 256 MiB per-iteration poison fill is usage-conditional).
    fused_mlp_v15<<<2048, 256, 0, stream>>>(X, M, W1, B1, W2, B2, W3, B3, OUT);
}

// Round 12
// 114.347 us; speedup vs baseline: 1.3293x; 1.3293x over previous
//
#include <hip/hip_runtime.h>
#include <math.h>

// (B,P,V,F,H) = (32,512,32,16,64). Round 16: v10 + register W-prefetch.
// v15 established: (1) the ~70-75us bench constant is UNCONDITIONAL harness
// cost (256MiB poison + resets run even with zero d_ws usage) -> only the
// fused kernel is a lever; (2) fused time is acutely sensitive to the
// W-load path (coalesced->strided = 46->77us): the per-wave chain of 34
// W-frag loads (WF 34KB > 32KB L1, thrashed by X -> L2 ~250cy each),
// serialized between dependent MFMAs, dominates wave lifetime. Occupancy
// can't hide it (every wave serializes identically; 26-70% occ all ~46us).
// Fix: hide W latency INTRA-wave:
//  - prefetch all 16 next-layerK W-frags into a register array: L2-frag
//    loads issued in the prologue (land under epi1's VALU/DS), L3-frag
//    loads issued inside layerK-L2's unrolled body right after each frag
//    is consumed (land under epi2). Static indexing, full unroll.
//  - __launch_bounds__(256,2): ~200 unified regs needed; occupancy proven
//    irrelevant, so 2 waves/SIMD is free. VGPR_Count ~180-210 = diagnostic
//    that the prefetch was honored (not sunk to use sites).
//  - rider: v11's extended conflict-free LDS swizzle (HW-validated verbatim,
//    compile-time folded; conflicts 5.24M -> ~0).
// Everything else v10 verbatim; prep_pack + d_ws restored (poison is free).
// MFMA 32x32x16_f16: A[m=l&31][k=8*(l>>5)+j], B[k][n=l&31],
//                    D[row=(r&3)+8*(r>>2)+4*(l>>5)][col=l&31].
namespace {

typedef _Float16 f16x8 __attribute__((ext_vector_type(8)));
typedef _Float16 f16x2 __attribute__((ext_vector_type(2)));
typedef float    f32x16 __attribute__((ext_vector_type(16)));
typedef unsigned int uint;

__device__ __forceinline__ uint pkrtz(float a, float b) {
    return __builtin_bit_cast(uint, __builtin_amdgcn_cvt_pkrtz(a, b));
}
__device__ __forceinline__ uint pk_add(uint a, uint b) {
    uint r; asm("v_pk_add_f16 %0, %1, %2" : "=v"(r) : "v"(a), "v"(b)); return r;
}
__device__ __forceinline__ uint pk_mul(uint a, uint b) {
    uint r; asm("v_pk_mul_f16 %0, %1, %2" : "=v"(r) : "v"(a), "v"(b)); return r;
}
__device__ __forceinline__ uint pk_max(uint a, uint b) {
    uint r; asm("v_pk_max_f16 %0, %1, %2" : "=v"(r) : "v"(a), "v"(b)); return r;
}

// ---- prep: pack W1/W2/W3 as f16 32x32x16 B-frags + per-bp u32 masks ----
// frag f: 0..1 = W1 (ki=0, nt2=f); 2..17 = W2 (ki=(f-2)>>1, nt2=(f-2)&1);
// 18..33 = W3. Lane l of frag f holds W[32*nt2 + (l&31)][16ki + 8*(l>>5)+j].
__global__ void prep_pack(const float* __restrict__ W1, const float* __restrict__ W2,
                          const float* __restrict__ W3, const int* __restrict__ M,
                          unsigned short* __restrict__ wsW, uint* __restrict__ wsM)
{
    int t = blockIdx.x * blockDim.x + threadIdx.x;
    if (t < 34 * 64) {
        int f = t >> 6, l = t & 63, nb = l & 31, kg = l >> 5;
        const float* src; int K, ki, nt2;
        if (f < 2)       { src = W1; K = 16;  ki = 0;           nt2 = f; }
        else if (f < 18) { int g = f - 2;  src = W2; K = 128; ki = g >> 1; nt2 = g & 1; }
        else             { int g = f - 18; src = W3; K = 128; ki = g >> 1; nt2 = g & 1; }
        const float* s = src + (size_t)(32 * nt2 + nb) * K + 16 * ki + 8 * kg;
        uint4 q;
        q.x = pkrtz(s[0], s[1]); q.y = pkrtz(s[2], s[3]);
        q.z = pkrtz(s[4], s[5]); q.w = pkrtz(s[6], s[7]);
        *(uint4*)(wsW + (size_t)f * 512 + l * 8) = q;
    } else if (t < 34 * 64 + 16384) {
        int bp = t - 34 * 64;
        const int4* mp = (const int4*)(M + bp * 32);
        uint bits = 0;
        #pragma unroll
        for (int i = 0; i < 8; ++i) {
            int4 v = mp[i];
            bits |= ((v.x ? 1u : 0u) | (v.y ? 2u : 0u) |
                     (v.z ? 4u : 0u) | (v.w ? 8u : 0u)) << (4 * i);
        }
        wsM[bp] = bits;
    }
}

__global__ __launch_bounds__(256, 2) void fused_mlp_v16(
    const float* __restrict__ X, const uint* __restrict__ MPK,
    const unsigned short* __restrict__ WF,
    const float* __restrict__ B1, const float* __restrict__ B2,
    const float* __restrict__ B3, float* __restrict__ OUT)
{
    __shared__ __align__(16) unsigned char sXb[4][2][4096];  // 32768 B
    __shared__ __align__(16) _Float16 sP[4][2][64];          //  1024 B

    const int t = threadIdx.x, w = t >> 6, l = t & 63;
    const int hb = l >> 5, mtl = (l >> 4) & 1, l3 = (l >> 3) & 1;
    const size_t bp0 = (size_t)blockIdx.x * 8 + w * 2;

    unsigned char* sb[2] = { &sXb[w][0][0], &sXb[w][1][0] };
    _Float16*     pl[2] = { &sP[w][0][0],  &sP[w][1][0]  };

    // v11 extended swizzle (HW-validated): write base, rows m..m+3 at col n.
    uint wb0 = (uint)((l & 7) * 32 + mtl * 256 + l3 * 1024 + hb * 8);
    wb0 ^= (uint)((mtl << 5) ^ (l3 << 4));
    const uint wb1 = (wb0 + 512u) ^ 64u;
    // read bases: parity pair (conflict-free reads).
    uint rbA = (uint)(mtl * 2048 + hb * 1024 + ((l & 15) >> 1) * 4);
    rbA ^= (uint)((hb << 4) ^ (mtl << 5));
    const uint rbB = rbA ^ 32u;
    const uint sel = (l & 1) ? 0x07060302u : 0x05040100u;  // own f16 half
    const uint SL2 = pkrtz(0.01f, 0.01f);

    const unsigned short* WFb = WF + l * 8;   // lane base into packed frags

    // ---- PREFETCH: issue L2-layer W-frag loads FIRST (land under epi1) ----
    uint4 wreg[16];
    #pragma unroll
    for (int f = 0; f < 16; ++f)
        wreg[f] = *(const uint4*)(WFb + (size_t)(2 + f) * 512);

    // ---- masks: packed -inf addends for pool (pairs of rows m,m+1) ----
    bool anyv[2]; uint adm[2][4][2];
    #pragma unroll
    for (int u = 0; u < 2; ++u) {
        uint mk = MPK[bp0 + u];
        anyv[u] = (mk != 0u);
        #pragma unroll
        for (int g = 0; g < 4; ++g) {   // rows 8g+4hb .. +3
            uint nib = (mk >> (8 * g + 4 * hb)) & 15u;
            adm[u][g][0] = (nib & 1u ? 0u : 0xFC00u) | (nib & 2u ? 0u : 0xFC000000u);
            adm[u][g][1] = (nib & 4u ? 0u : 0xFC00u) | (nib & 8u ? 0u : 0xFC000000u);
        }
    }

    // ---- X -> layer-1 A-frags (f16, rtz) ----
    f16x8 a1f[2];
    #pragma unroll
    for (int u = 0; u < 2; ++u) {
        const float4* xp = (const float4*)(X + ((bp0 + u) * 32 + (l & 31)) * 16 + 8 * hb);
        float4 x0 = xp[0], x1 = xp[1];
        uint4 q;
        q.x = pkrtz(x0.x, x0.y); q.y = pkrtz(x0.z, x0.w);
        q.z = pkrtz(x1.x, x1.y); q.w = pkrtz(x1.z, x1.w);
        a1f[u] = __builtin_bit_cast(f16x8, q);
    }

    // persistent zero C-input
    f32x16 zc;
    #pragma unroll
    for (int i = 0; i < 16; ++i) zc[i] = 0.f;

    f32x16 acc[2][2];   // [u][nt2]

    // ---- layer 1 (K=16, one 32x32x16 step) ----
    {
        f16x8 wf0 = *(const f16x8*)(WFb);
        f16x8 wf1 = *(const f16x8*)(WFb + 512);
        #pragma unroll
        for (int u = 0; u < 2; ++u) {
            acc[u][0] = __builtin_amdgcn_mfma_f32_32x32x16_f16(a1f[u], wf0, zc, 0, 0, 0);
            acc[u][1] = __builtin_amdgcn_mfma_f32_32x32x16_f16(a1f[u], wf1, zc, 0, 0, 0);
        }
    }

    // ---- epilogue: +bias, lrelu, (store h to swizzled LDS), masked pool ----
    auto epi = [&](int u, const float* __restrict__ Bp, bool dostore) {
        unsigned char* sbu = sb[u];
        _Float16* plu = pl[u];
        #pragma unroll
        for (int nt2 = 0; nt2 < 2; ++nt2) {
            float bsc = Bp[32 * nt2 + (l & 31)];
            uint bpk = pkrtz(bsc, bsc);
            uint base = nt2 ? wb1 : wb0;
            uint pp = 0xFC00FC00u;   // (-inf, -inf)
            #pragma unroll
            for (int g = 0; g < 4; ++g) {   // rows m = 8g+4hb .. +3
                uint d01 = pkrtz(acc[u][nt2][4 * g + 0], acc[u][nt2][4 * g + 1]);
                uint d23 = pkrtz(acc[u][nt2][4 * g + 2], acc[u][nt2][4 * g + 3]);
                d01 = pk_add(d01, bpk);  d23 = pk_add(d23, bpk);
                d01 = pk_max(d01, pk_mul(d01, SL2));      // packed lrelu
                d23 = pk_max(d23, pk_mul(d23, SL2));
                if (dostore) {
                    uint wba = (base ^ (uint)(((g & 1) << 4) ^ ((g >> 1) << 5)))
                               + (uint)((g >> 1) * 2048);
                    uint2 st; st.x = d01; st.y = d23;
                    *(uint2*)(sbu + wba) = st;
                }
                pp = pk_max(pp, pk_add(d01, adm[u][g][0]));
                pp = pk_max(pp, pk_add(d23, adm[u][g][1]));
            }
            f16x2 ph = __builtin_bit_cast(f16x2, pp);
            float pv = fmaxf((float)ph[0], (float)ph[1]);
            pv = fmaxf(pv, __shfl_xor(pv, 32));   // merge other hb half
            pv = anyv[u] ? pv : 0.f;
            if (dostore) {
                if (l < 32) plu[32 * nt2 + (l & 31)] = (_Float16)pv;
            } else {
                if (l < 32) OUT[(bp0 + u) * 64 + 32 * nt2 + (l & 31)] = pv;
            }
        }
    };

    // ---- K=128 layer from wreg; optionally REFILL wreg with next layer's
    //      frags right after each pair is consumed (loads land under the
    //      following epilogue) ----
    auto layerK = [&](bool refill, int fb_next) {
        #pragma unroll
        for (int ki = 0; ki < 8; ++ki) {
            f16x8 wf0 = __builtin_bit_cast(f16x8, wreg[2 * ki]);
            f16x8 wf1 = __builtin_bit_cast(f16x8, wreg[2 * ki + 1]);
            #pragma unroll
            for (int u = 0; u < 2; ++u) {
                f16x8 a;
                if (ki < 4) {
                    const unsigned char* pA = sb[u] + rbA + 256 * ki;
                    const unsigned char* pB = sb[u] + rbB + 256 * ki;
                    uint F[8];
                    #pragma unroll
                    for (int j = 0; j < 8; ++j) {
                        const int e = j ^ ki;
                        F[j] = *(const uint*)(((e & 1) ? pB : pA) + 32 * (e & ~1));
                    }
                    uint4 q;
                    q.x = __builtin_amdgcn_perm(F[1], F[0], sel);
                    q.y = __builtin_amdgcn_perm(F[3], F[2], sel);
                    q.z = __builtin_amdgcn_perm(F[5], F[4], sel);
                    q.w = __builtin_amdgcn_perm(F[7], F[6], sel);
                    a = __builtin_bit_cast(f16x8, q);
                } else {
                    a = *(const f16x8*)(pl[u] + 16 * (ki - 4) + 8 * hb);  // bcast
                }
                acc[u][0] = __builtin_amdgcn_mfma_f32_32x32x16_f16(
                    a, wf0, ki == 0 ? zc : acc[u][0], 0, 0, 0);
                acc[u][1] = __builtin_amdgcn_mfma_f32_32x32x16_f16(
                    a, wf1, ki == 0 ? zc : acc[u][1], 0, 0, 0);
            }
            if (refill) {
                wreg[2 * ki]     = *(const uint4*)(WFb + (size_t)(fb_next + 2 * ki) * 512);
                wreg[2 * ki + 1] = *(const uint4*)(WFb + (size_t)(fb_next + 2 * ki + 1) * 512);
            }
        }
    };

    epi(0, B1, true);  epi(1, B1, true);    // L2 W-loads land here
    layerK(true, 18);                        // consume L2, issue L3 loads
    epi(0, B2, true);  epi(1, B2, true);    // L3 W-loads land here
    layerK(false, 0);
    epi(0, B3, false); epi(1, B3, false);   // layer-3 pool == final output
}
} // namespace

extern "C" void kernel_launch(void* const* d_in, const int* in_sizes, int n_in,
                              void* d_out, int out_size, void* d_ws, size_t ws_size,
                              hipStream_t stream) {
    (void)in_sizes; (void)n_in; (void)ws_size; (void)out_size;
    const float* X  = (const float*)d_in[0];
    const int*   M  = (const int*)d_in[1];
    const float* W1 = (const float*)d_in[2];
    const float* B1 = (const float*)d_in[3];
    const float* W2 = (const float*)d_in[4];
    const float* B2 = (const float*)d_in[5];
    const float* W3 = (const float*)d_in[6];
    const float* B3 = (const float*)d_in[7];
    float* OUT = (float*)d_out;

    unsigned short* WF  = (unsigned short*)d_ws;              // 34816 B
    uint*           MPK = (uint*)((char*)d_ws + 34816);       // 65536 B

    prep_pack<<<(34 * 64 + 16384 + 255) / 256, 256, 0, stream>>>(W1, W2, W3, M, WF, MPK);
    // 2048 blocks x 4 waves x 2 bp = 16384 bp; two bp per wave
    fused_mlp_v16<<<2048, 256, 0, stream>>>(X, MPK, WF, B1, B2, B3, OUT);
}